// Round 2
// baseline (3637.526 us; speedup 1.0000x reference)
//
#include <hip/hip_runtime.h>

// GCN: 3x (h@W -> edge-normalized scatter-add + self-loop + bias [-> ReLU])
// Outputs: concat(x, h1, h2, h3), each [N,64] fp32.
// edge_index arrives as int32 (harness converts integer inputs to int32).

#define TPB 256

__global__ __launch_bounds__(TPB) void k_init_deg(float* __restrict__ deg, int n) {
    int i = blockIdx.x * TPB + threadIdx.x;
    if (i < n) deg[i] = 1.0f;  // self-loop weight
}

__global__ __launch_bounds__(TPB) void k_deg_scatter(const int* __restrict__ col,
                                                     const float* __restrict__ w,
                                                     float* __restrict__ deg, int E) {
    int e = blockIdx.x * TPB + threadIdx.x;
    if (e < E) atomicAdd(&deg[col[e]], w[e]);
}

__global__ __launch_bounds__(TPB) void k_dinv(float* __restrict__ deg, int n) {
    int i = blockIdx.x * TPB + threadIdx.x;
    if (i < n) {
        float d = deg[i];
        deg[i] = d > 0.f ? rsqrtf(d) : 0.f;
    }
}

// out[N,64] = in[N,64] @ W[64,64]; W and 4 input rows staged in LDS.
__global__ __launch_bounds__(TPB) void k_gemm64(const float* __restrict__ in,
                                                const float* __restrict__ Wg,
                                                float* __restrict__ out, int n) {
    __shared__ float Ws[64 * 64];
    __shared__ float Is[4 * 64];
    int tid = threadIdx.x;
    #pragma unroll
    for (int i = 0; i < 16; ++i) Ws[i * TPB + tid] = Wg[i * TPB + tid];
    int rowbase = blockIdx.x * 4;
    {
        int r = rowbase + (tid >> 6), k = tid & 63;
        Is[tid] = (r < n) ? in[(size_t)r * 64 + k] : 0.f;
    }
    __syncthreads();
    int j = tid & 63, r = tid >> 6;
    int row = rowbase + r;
    if (row >= n) return;
    float acc = 0.f;
    #pragma unroll
    for (int k = 0; k < 64; ++k) acc = fmaf(Is[r * 64 + k], Ws[k * 64 + j], acc);
    out[(size_t)row * 64 + j] = acc;
}

// out[i,:] = hw[i,:] * dinv[i]^2 + b[:]   (self-loop term + bias; float4 lanes)
__global__ __launch_bounds__(TPB) void k_selfinit(const float* __restrict__ hw,
                                                  const float* __restrict__ dinv,
                                                  const float* __restrict__ b,
                                                  float* __restrict__ out, int n) {
    int idx = blockIdx.x * TPB + threadIdx.x;
    if (idx >= n * 16) return;
    int i = idx >> 4, c = (idx & 15) << 2;
    float di = dinv[i];
    float s = di * di;
    float4 h = *(const float4*)&hw[(size_t)i * 64 + c];
    float4 bb = *(const float4*)&b[c];
    float4 o;
    o.x = fmaf(h.x, s, bb.x);
    o.y = fmaf(h.y, s, bb.y);
    o.z = fmaf(h.z, s, bb.z);
    o.w = fmaf(h.w, s, bb.w);
    *(float4*)&out[(size_t)i * 64 + c] = o;
}

// 16 threads per edge, 4 floats each: out[col,:] += dinv[row]*w*dinv[col] * hw[row,:]
__global__ __launch_bounds__(TPB) void k_scatter(const int* __restrict__ row,
                                                 const int* __restrict__ col,
                                                 const float* __restrict__ w,
                                                 const float* __restrict__ dinv,
                                                 const float* __restrict__ hw,
                                                 float* __restrict__ out, int E) {
    int idx = blockIdx.x * TPB + threadIdx.x;
    int e = idx >> 4;
    if (e >= E) return;
    int f = (idx & 15) << 2;
    int r = row[e], c = col[e];
    float nm = dinv[r] * w[e] * dinv[c];
    float4 h = *(const float4*)&hw[(size_t)r * 64 + f];
    float* o = &out[(size_t)c * 64 + f];
    atomicAdd(o + 0, h.x * nm);
    atomicAdd(o + 1, h.y * nm);
    atomicAdd(o + 2, h.z * nm);
    atomicAdd(o + 3, h.w * nm);
}

__global__ __launch_bounds__(TPB) void k_relu4(float* __restrict__ p, int n16) {
    int idx = blockIdx.x * TPB + threadIdx.x;
    if (idx >= n16) return;
    float4 v = *(float4*)&p[(size_t)idx * 4];
    v.x = v.x > 0.f ? v.x : 0.f;
    v.y = v.y > 0.f ? v.y : 0.f;
    v.z = v.z > 0.f ? v.z : 0.f;
    v.w = v.w > 0.f ? v.w : 0.f;
    *(float4*)&p[(size_t)idx * 4] = v;
}

extern "C" void kernel_launch(void* const* d_in, const int* in_sizes, int n_in,
                              void* d_out, int out_size, void* d_ws, size_t ws_size,
                              hipStream_t stream) {
    const float* x = (const float*)d_in[0];
    const int* ei = (const int*)d_in[1];      // int32 on device
    const float* ew = (const float*)d_in[2];
    const float* Wl[3] = {(const float*)d_in[3], (const float*)d_in[5], (const float*)d_in[7]};
    const float* Bl[3] = {(const float*)d_in[4], (const float*)d_in[6], (const float*)d_in[8]};

    const int n = in_sizes[0] / 64;
    const int E = in_sizes[2];
    const int* row = ei;       // edge_index[0]
    const int* col = ei + E;   // edge_index[1]
    float* out = (float*)d_out;

    // workspace layout (256B aligned): dinv[n] | hw[n*64]  (~26 MB)
    char* ws = (char*)d_ws;
    size_t off1 = ((size_t)n * 4 + 255) & ~(size_t)255;
    float* dinv = (float*)ws;
    float* hw   = (float*)(ws + off1);

    // output 0 = x
    hipMemcpyAsync(out, x, (size_t)n * 64 * sizeof(float), hipMemcpyDeviceToDevice, stream);

    k_init_deg<<<(n + TPB - 1) / TPB, TPB, 0, stream>>>(dinv, n);
    k_deg_scatter<<<(E + TPB - 1) / TPB, TPB, 0, stream>>>(col, ew, dinv, E);
    k_dinv<<<(n + TPB - 1) / TPB, TPB, 0, stream>>>(dinv, n);

    const float* hin = x;
    for (int L = 0; L < 3; ++L) {
        float* oseg = out + (size_t)(L + 1) * n * 64;
        k_gemm64<<<(n + 3) / 4, TPB, 0, stream>>>(hin, Wl[L], hw, n);
        k_selfinit<<<(n * 16 + TPB - 1) / TPB, TPB, 0, stream>>>(hw, dinv, Bl[L], oseg, n);
        k_scatter<<<(E * 16 + TPB - 1) / TPB, TPB, 0, stream>>>(row, col, ew, dinv, hw, oseg, E);
        if (L < 2) k_relu4<<<(n * 16 + TPB - 1) / TPB, TPB, 0, stream>>>(oseg, n * 16);
        hin = oseg;
    }
}

// Round 3
// 650.850 us; speedup vs baseline: 5.5889x; 5.5889x over previous
//
#include <hip/hip_runtime.h>

// GCN: 3x (h@W -> gather-aggregate via CSR-by-dest + self-loop + bias [-> ReLU])
// Outputs: concat(x, h1, h2, h3), each [N,64] fp32.
// Atomic scatter replaced by CSR build (once/call) + deterministic gather.

#define TPB 256
#define SCAN_B 1024

__global__ __launch_bounds__(TPB) void k_init_deg(float* __restrict__ deg, int n) {
    int i = blockIdx.x * TPB + threadIdx.x;
    if (i < n) deg[i] = 1.0f;  // self-loop weight
}

__global__ __launch_bounds__(TPB) void k_deg_scatter(const int* __restrict__ col,
                                                     const float* __restrict__ w,
                                                     float* __restrict__ deg, int E) {
    int e = blockIdx.x * TPB + threadIdx.x;
    if (e < E) atomicAdd(&deg[col[e]], w[e]);
}

__global__ __launch_bounds__(TPB) void k_dinv(float* __restrict__ deg, int n) {
    int i = blockIdx.x * TPB + threadIdx.x;
    if (i < n) {
        float d = deg[i];
        deg[i] = d > 0.f ? rsqrtf(d) : 0.f;
    }
}

__global__ __launch_bounds__(TPB) void k_hist(const int* __restrict__ col,
                                              int* __restrict__ hist, int E) {
    int e = blockIdx.x * TPB + threadIdx.x;
    if (e < E) atomicAdd(&hist[col[e]], 1);
}

// Block-level exclusive scan (Hillis-Steele in LDS), block sums out.
__global__ __launch_bounds__(SCAN_B) void k_scan1(const int* __restrict__ hist,
                                                  int* __restrict__ starts,
                                                  int* __restrict__ bsum, int n) {
    __shared__ int s[SCAN_B];
    int tid = threadIdx.x;
    int i = blockIdx.x * SCAN_B + tid;
    int v = (i < n) ? hist[i] : 0;
    s[tid] = v;
    __syncthreads();
    for (int off = 1; off < SCAN_B; off <<= 1) {
        int t = (tid >= off) ? s[tid - off] : 0;
        __syncthreads();
        s[tid] += t;
        __syncthreads();
    }
    if (i < n) starts[i] = s[tid] - v;          // exclusive, block-local
    if (tid == SCAN_B - 1) bsum[blockIdx.x] = s[SCAN_B - 1];
}

__global__ void k_scan2(int* __restrict__ bsum, int nb) {
    if (threadIdx.x == 0 && blockIdx.x == 0) {
        int acc = 0;
        for (int i = 0; i < nb; ++i) { int t = bsum[i]; bsum[i] = acc; acc += t; }
    }
}

__global__ __launch_bounds__(SCAN_B) void k_scan3(int* __restrict__ starts,
                                                  int* __restrict__ cursor,
                                                  const int* __restrict__ bsum,
                                                  int n, int E) {
    int i = blockIdx.x * SCAN_B + threadIdx.x;
    if (i < n) {
        int v = starts[i] + bsum[blockIdx.x];
        starts[i] = v;
        cursor[i] = v;
    }
    if (i == 0) starts[n] = E;
}

// Scatter edges into CSR slots: edges[p] = (src, norm) with norm precomputed.
__global__ __launch_bounds__(TPB) void k_fill(const int* __restrict__ row,
                                              const int* __restrict__ col,
                                              const float* __restrict__ w,
                                              const float* __restrict__ dinv,
                                              int* __restrict__ cursor,
                                              int2* __restrict__ edges, int E) {
    int e = blockIdx.x * TPB + threadIdx.x;
    if (e >= E) return;
    int r = row[e], c = col[e];
    int p = atomicAdd(&cursor[c], 1);
    edges[p] = make_int2(r, __float_as_int(dinv[r] * w[e] * dinv[c]));
}

// out[N,64] = in[N,64] @ W[64,64]; W and 4 input rows staged in LDS.
__global__ __launch_bounds__(TPB) void k_gemm64(const float* __restrict__ in,
                                                const float* __restrict__ Wg,
                                                float* __restrict__ out, int n) {
    __shared__ float Ws[64 * 64];
    __shared__ float Is[4 * 64];
    int tid = threadIdx.x;
    #pragma unroll
    for (int i = 0; i < 16; ++i) Ws[i * TPB + tid] = Wg[i * TPB + tid];
    int rowbase = blockIdx.x * 4;
    {
        int r = rowbase + (tid >> 6), k = tid & 63;
        Is[tid] = (r < n) ? in[(size_t)r * 64 + k] : 0.f;
    }
    __syncthreads();
    int j = tid & 63, r = tid >> 6;
    int row = rowbase + r;
    if (row >= n) return;
    float acc = 0.f;
    #pragma unroll
    for (int k = 0; k < 64; ++k) acc = fmaf(Is[r * 64 + k], Ws[k * 64 + j], acc);
    out[(size_t)row * 64 + j] = acc;
}

// 16 threads/node, float4 feature lanes: gather incident edges, fuse
// self-loop + bias + optional ReLU, single write per output element.
__global__ __launch_bounds__(TPB) void k_gather(const int* __restrict__ starts,
                                                const int2* __restrict__ edges,
                                                const float* __restrict__ hw,
                                                const float* __restrict__ dinv,
                                                const float* __restrict__ b,
                                                float* __restrict__ out,
                                                int n, int relu) {
    int idx = blockIdx.x * TPB + threadIdx.x;
    int node = idx >> 4;
    if (node >= n) return;
    int f = (idx & 15) << 2;
    int s0 = starts[node], s1 = starts[node + 1];
    float di = dinv[node];
    float sc = di * di;
    float4 hself = *(const float4*)&hw[(size_t)node * 64 + f];
    float4 bb = *(const float4*)&b[f];
    float4 acc;
    acc.x = fmaf(hself.x, sc, bb.x);
    acc.y = fmaf(hself.y, sc, bb.y);
    acc.z = fmaf(hself.z, sc, bb.z);
    acc.w = fmaf(hself.w, sc, bb.w);
    for (int e = s0; e < s1; ++e) {
        int2 ed = edges[e];
        float nm = __int_as_float(ed.y);
        float4 h = *(const float4*)&hw[(size_t)ed.x * 64 + f];
        acc.x = fmaf(h.x, nm, acc.x);
        acc.y = fmaf(h.y, nm, acc.y);
        acc.z = fmaf(h.z, nm, acc.z);
        acc.w = fmaf(h.w, nm, acc.w);
    }
    if (relu) {
        acc.x = acc.x > 0.f ? acc.x : 0.f;
        acc.y = acc.y > 0.f ? acc.y : 0.f;
        acc.z = acc.z > 0.f ? acc.z : 0.f;
        acc.w = acc.w > 0.f ? acc.w : 0.f;
    }
    *(float4*)&out[(size_t)node * 64 + f] = acc;
}

extern "C" void kernel_launch(void* const* d_in, const int* in_sizes, int n_in,
                              void* d_out, int out_size, void* d_ws, size_t ws_size,
                              hipStream_t stream) {
    const float* x = (const float*)d_in[0];
    const int* ei = (const int*)d_in[1];      // int32 on device
    const float* ew = (const float*)d_in[2];
    const float* Wl[3] = {(const float*)d_in[3], (const float*)d_in[5], (const float*)d_in[7]};
    const float* Bl[3] = {(const float*)d_in[4], (const float*)d_in[6], (const float*)d_in[8]};

    const int n = in_sizes[0] / 64;
    const int E = in_sizes[2];
    const int* row = ei;       // edge_index[0]
    const int* col = ei + E;   // edge_index[1]
    float* out = (float*)d_out;

    const int NB = (n + SCAN_B - 1) / SCAN_B;

    // workspace layout (256B aligned):
    // dinv[n] f32 | hw[n*64] f32 | starts[n+1] i32 | cursor[n] i32 | bsum[NB] i32 | edges[E] int2
    char* ws = (char*)d_ws;
    size_t o = 0;
    float* dinv = (float*)(ws + o);   o = (o + (size_t)n * 4 + 255) & ~(size_t)255;
    float* hw   = (float*)(ws + o);   o = (o + (size_t)n * 256 + 255) & ~(size_t)255;
    int* starts = (int*)(ws + o);     o = (o + (size_t)(n + 1) * 4 + 255) & ~(size_t)255;
    int* cursor = (int*)(ws + o);     o = (o + (size_t)n * 4 + 255) & ~(size_t)255;
    int* bsum   = (int*)(ws + o);     o = (o + (size_t)NB * 4 + 255) & ~(size_t)255;
    int2* edges = (int2*)(ws + o);

    // output 0 = x
    hipMemcpyAsync(out, x, (size_t)n * 64 * sizeof(float), hipMemcpyDeviceToDevice, stream);

    // dinv
    k_init_deg<<<(n + TPB - 1) / TPB, TPB, 0, stream>>>(dinv, n);
    k_deg_scatter<<<(E + TPB - 1) / TPB, TPB, 0, stream>>>(col, ew, dinv, E);
    k_dinv<<<(n + TPB - 1) / TPB, TPB, 0, stream>>>(dinv, n);

    // CSR by destination (cursor doubles as histogram)
    hipMemsetAsync(cursor, 0, (size_t)n * 4, stream);
    k_hist<<<(E + TPB - 1) / TPB, TPB, 0, stream>>>(col, cursor, E);
    k_scan1<<<NB, SCAN_B, 0, stream>>>(cursor, starts, bsum, n);
    k_scan2<<<1, 64, 0, stream>>>(bsum, NB);
    k_scan3<<<NB, SCAN_B, 0, stream>>>(starts, cursor, bsum, n, E);
    k_fill<<<(E + TPB - 1) / TPB, TPB, 0, stream>>>(row, col, ew, dinv, cursor, edges, E);

    const float* hin = x;
    for (int L = 0; L < 3; ++L) {
        float* oseg = out + (size_t)(L + 1) * n * 64;
        k_gemm64<<<(n + 3) / 4, TPB, 0, stream>>>(hin, Wl[L], hw, n);
        k_gather<<<(n * 16 + TPB - 1) / TPB, TPB, 0, stream>>>(starts, edges, hw, dinv, Bl[L], oseg, n, L < 2 ? 1 : 0);
        hin = oseg;
    }
}

// Round 4
// 570.760 us; speedup vs baseline: 6.3731x; 1.1403x over previous
//
#include <hip/hip_runtime.h>

// GCN: 3x (h@W -> gather-aggregate via CSR-by-dest + self-loop + bias [-> ReLU])
// Outputs: concat(x, h1, h2, h3), each [N,64] fp32.
// Degrees/norms computed atomic-free from CSR; only hist+fill keep 1 int atomic/edge.

#define TPB 256
#define SCAN_B 1024
#define GR 16  // gemm rows per block

__global__ __launch_bounds__(TPB) void k_hist(const int* __restrict__ col,
                                              int* __restrict__ hist, int E) {
    int e = blockIdx.x * TPB + threadIdx.x;
    if (e < E) atomicAdd(&hist[col[e]], 1);
}

// Block-level exclusive scan (Hillis-Steele in LDS), block sums out.
__global__ __launch_bounds__(SCAN_B) void k_scan1(const int* __restrict__ hist,
                                                  int* __restrict__ starts,
                                                  int* __restrict__ bsum, int n) {
    __shared__ int s[SCAN_B];
    int tid = threadIdx.x;
    int i = blockIdx.x * SCAN_B + tid;
    int v = (i < n) ? hist[i] : 0;
    s[tid] = v;
    __syncthreads();
    for (int off = 1; off < SCAN_B; off <<= 1) {
        int t = (tid >= off) ? s[tid - off] : 0;
        __syncthreads();
        s[tid] += t;
        __syncthreads();
    }
    if (i < n) starts[i] = s[tid] - v;          // exclusive, block-local
    if (tid == SCAN_B - 1) bsum[blockIdx.x] = s[SCAN_B - 1];
}

__global__ void k_scan2(int* __restrict__ bsum, int nb) {
    if (threadIdx.x == 0 && blockIdx.x == 0) {
        int acc = 0;
        for (int i = 0; i < nb; ++i) { int t = bsum[i]; bsum[i] = acc; acc += t; }
    }
}

__global__ __launch_bounds__(SCAN_B) void k_scan3(int* __restrict__ starts,
                                                  int* __restrict__ cursor,
                                                  const int* __restrict__ bsum,
                                                  int n, int E) {
    int i = blockIdx.x * SCAN_B + threadIdx.x;
    if (i < n) {
        int v = starts[i] + bsum[blockIdx.x];
        starts[i] = v;
        cursor[i] = v;
    }
    if (i == 0) starts[n] = E;
}

// Scatter edges into CSR slots: edges[p] = (src, raw weight).
__global__ __launch_bounds__(TPB) void k_fill(const int* __restrict__ row,
                                              const int* __restrict__ col,
                                              const float* __restrict__ w,
                                              int* __restrict__ cursor,
                                              int2* __restrict__ edges, int E) {
    int e = blockIdx.x * TPB + threadIdx.x;
    if (e >= E) return;
    int p = atomicAdd(&cursor[col[e]], 1);
    edges[p] = make_int2(row[e], __float_as_int(w[e]));
}

// Atomic-free: deg[node] = 1 + sum of incident w; dinv = rsqrt(deg).
__global__ __launch_bounds__(TPB) void k_degdinv(const int* __restrict__ starts,
                                                 const int2* __restrict__ edges,
                                                 float* __restrict__ dinv, int n) {
    int i = blockIdx.x * TPB + threadIdx.x;
    if (i >= n) return;
    int s0 = starts[i], s1 = starts[i + 1];
    float d = 1.0f;  // self-loop
    for (int s = s0; s < s1; ++s) d += __int_as_float(edges[s].y);
    dinv[i] = d > 0.f ? rsqrtf(d) : 0.f;
}

// In-place: edges[s].y = dinv[src] * w * dinv[dest].
__global__ __launch_bounds__(TPB) void k_normcsr(const int* __restrict__ starts,
                                                 const float* __restrict__ dinv,
                                                 int2* __restrict__ edges, int n) {
    int i = blockIdx.x * TPB + threadIdx.x;
    if (i >= n) return;
    int s0 = starts[i], s1 = starts[i + 1];
    float dn = dinv[i];
    for (int s = s0; s < s1; ++s) {
        int2 ed = edges[s];
        edges[s].y = __float_as_int(dinv[ed.x] * __int_as_float(ed.y) * dn);
    }
}

// out[N,64] = in[N,64] @ W[64,64]; W + GR input rows in LDS, 4 outputs/thread.
__global__ __launch_bounds__(TPB) void k_gemm64(const float* __restrict__ in,
                                                const float* __restrict__ Wg,
                                                float* __restrict__ out, int n) {
    __shared__ float Ws[64 * 64];
    __shared__ float Is[GR * 64];
    int tid = threadIdx.x;
    #pragma unroll
    for (int i = 0; i < 16; ++i) Ws[i * TPB + tid] = Wg[i * TPB + tid];
    int rowbase = blockIdx.x * GR;
    {
        int r = rowbase + (tid >> 4);           // 16 threads per row, float4 each
        int c = (tid & 15) << 2;
        float4 v = make_float4(0.f, 0.f, 0.f, 0.f);
        if (r < n) v = *(const float4*)&in[(size_t)r * 64 + c];
        *(float4*)&Is[(tid >> 4) * 64 + c] = v;
    }
    __syncthreads();
    int j = tid & 63, rgrp = tid >> 6;          // rgrp in [0,4)
    float acc[4] = {0.f, 0.f, 0.f, 0.f};
    #pragma unroll 16
    for (int k = 0; k < 64; ++k) {
        float wv = Ws[k * 64 + j];
        #pragma unroll
        for (int rr = 0; rr < 4; ++rr)
            acc[rr] = fmaf(Is[(rgrp * 4 + rr) * 64 + k], wv, acc[rr]);
    }
    #pragma unroll
    for (int rr = 0; rr < 4; ++rr) {
        int r = rowbase + rgrp * 4 + rr;
        if (r < n) out[(size_t)r * 64 + j] = acc[rr];
    }
}

// 16 threads/node, float4 feature lanes: gather incident edges, fuse
// self-loop + bias + optional ReLU, single write per output element.
__global__ __launch_bounds__(TPB) void k_gather(const int* __restrict__ starts,
                                                const int2* __restrict__ edges,
                                                const float* __restrict__ hw,
                                                const float* __restrict__ dinv,
                                                const float* __restrict__ b,
                                                float* __restrict__ out,
                                                int n, int relu) {
    int idx = blockIdx.x * TPB + threadIdx.x;
    int node = idx >> 4;
    if (node >= n) return;
    int f = (idx & 15) << 2;
    int s0 = starts[node], s1 = starts[node + 1];
    float di = dinv[node];
    float sc = di * di;
    float4 hself = *(const float4*)&hw[(size_t)node * 64 + f];
    float4 bb = *(const float4*)&b[f];
    float4 acc;
    acc.x = fmaf(hself.x, sc, bb.x);
    acc.y = fmaf(hself.y, sc, bb.y);
    acc.z = fmaf(hself.z, sc, bb.z);
    acc.w = fmaf(hself.w, sc, bb.w);
    for (int e = s0; e < s1; ++e) {
        int2 ed = edges[e];
        float nm = __int_as_float(ed.y);
        float4 h = *(const float4*)&hw[(size_t)ed.x * 64 + f];
        acc.x = fmaf(h.x, nm, acc.x);
        acc.y = fmaf(h.y, nm, acc.y);
        acc.z = fmaf(h.z, nm, acc.z);
        acc.w = fmaf(h.w, nm, acc.w);
    }
    if (relu) {
        acc.x = acc.x > 0.f ? acc.x : 0.f;
        acc.y = acc.y > 0.f ? acc.y : 0.f;
        acc.z = acc.z > 0.f ? acc.z : 0.f;
        acc.w = acc.w > 0.f ? acc.w : 0.f;
    }
    *(float4*)&out[(size_t)node * 64 + f] = acc;
}

extern "C" void kernel_launch(void* const* d_in, const int* in_sizes, int n_in,
                              void* d_out, int out_size, void* d_ws, size_t ws_size,
                              hipStream_t stream) {
    const float* x = (const float*)d_in[0];
    const int* ei = (const int*)d_in[1];      // int32 on device
    const float* ew = (const float*)d_in[2];
    const float* Wl[3] = {(const float*)d_in[3], (const float*)d_in[5], (const float*)d_in[7]};
    const float* Bl[3] = {(const float*)d_in[4], (const float*)d_in[6], (const float*)d_in[8]};

    const int n = in_sizes[0] / 64;
    const int E = in_sizes[2];
    const int* row = ei;       // edge_index[0]
    const int* col = ei + E;   // edge_index[1]
    float* out = (float*)d_out;

    const int NB = (n + SCAN_B - 1) / SCAN_B;

    // workspace layout (256B aligned):
    // dinv[n] | hw[n*64] | starts[n+1] | cursor[n] | bsum[NB] | edges[E] int2
    char* ws = (char*)d_ws;
    size_t o = 0;
    float* dinv = (float*)(ws + o);   o = (o + (size_t)n * 4 + 255) & ~(size_t)255;
    float* hw   = (float*)(ws + o);   o = (o + (size_t)n * 256 + 255) & ~(size_t)255;
    int* starts = (int*)(ws + o);     o = (o + (size_t)(n + 1) * 4 + 255) & ~(size_t)255;
    int* cursor = (int*)(ws + o);     o = (o + (size_t)n * 4 + 255) & ~(size_t)255;
    int* bsum   = (int*)(ws + o);     o = (o + (size_t)NB * 4 + 255) & ~(size_t)255;
    int2* edges = (int2*)(ws + o);

    // output 0 = x
    hipMemcpyAsync(out, x, (size_t)n * 64 * sizeof(float), hipMemcpyDeviceToDevice, stream);

    // CSR by destination (cursor doubles as histogram)
    hipMemsetAsync(cursor, 0, (size_t)n * 4, stream);
    k_hist<<<(E + TPB - 1) / TPB, TPB, 0, stream>>>(col, cursor, E);
    k_scan1<<<NB, SCAN_B, 0, stream>>>(cursor, starts, bsum, n);
    k_scan2<<<1, 64, 0, stream>>>(bsum, NB);
    k_scan3<<<NB, SCAN_B, 0, stream>>>(starts, cursor, bsum, n, E);
    k_fill<<<(E + TPB - 1) / TPB, TPB, 0, stream>>>(row, col, ew, cursor, edges, E);

    // degrees + norms from CSR, atomic-free
    k_degdinv<<<(n + TPB - 1) / TPB, TPB, 0, stream>>>(starts, edges, dinv, n);
    k_normcsr<<<(n + TPB - 1) / TPB, TPB, 0, stream>>>(starts, dinv, edges, n);

    const float* hin = x;
    for (int L = 0; L < 3; ++L) {
        float* oseg = out + (size_t)(L + 1) * n * 64;
        k_gemm64<<<(n + GR - 1) / GR, TPB, 0, stream>>>(hin, Wl[L], hw, n);
        k_gather<<<(n * 16 + TPB - 1) / TPB, TPB, 0, stream>>>(starts, edges, hw, dinv, Bl[L], oseg, n, L < 2 ? 1 : 0);
        hin = oseg;
    }
}

// Round 5
// 489.325 us; speedup vs baseline: 7.4338x; 1.1664x over previous
//
#include <hip/hip_runtime.h>

// GCN: 3x (h@W -> gather-aggregate via CSR-by-dest + self-loop + bias [-> ReLU])
// Outputs: concat(x, h1, h2, h3), each [N,64] fp32.
// CSR built by 2-level counting sort (coalesced writes, no per-edge global atomics).

#define TPB 256
#define P1_CHUNK 8192   // edges per block in pass0/pass1
#define DSH 7           // coarse bucket = dest >> DSH (128 dests/bucket)
#define DNB 128         // dests per bucket
#define STAGE_CAP 4096  // pass-2 LDS staging capacity (edges)

// ---- Pass 0: coarse histogram (per-block LDS hist, merged with few global atomics)
__global__ __launch_bounds__(TPB) void k_p0(const int* __restrict__ col,
                                            int* __restrict__ chist, int E, int nbk) {
    __shared__ int h[1024];
    int tid = threadIdx.x;
    for (int i = tid; i < nbk; i += TPB) h[i] = 0;
    __syncthreads();
    int s0 = blockIdx.x * P1_CHUNK;
    int s1 = min(s0 + P1_CHUNK, E);
    for (int i = s0 + tid; i < s1; i += TPB) atomicAdd(&h[col[i] >> DSH], 1);
    __syncthreads();
    for (int i = tid; i < nbk; i += TPB)
        if (h[i]) atomicAdd(&chist[i], h[i]);
}

// ---- Scan coarse buckets (single block), init cursor copy.
__global__ __launch_bounds__(1024) void k_scanb(const int* __restrict__ chist,
                                                int* __restrict__ cbase,
                                                int* __restrict__ ccur, int nbk, int E) {
    __shared__ int s[1024];
    int tid = threadIdx.x;
    int v = (tid < nbk) ? chist[tid] : 0;
    s[tid] = v;
    __syncthreads();
    for (int off = 1; off < 1024; off <<= 1) {
        int t = (tid >= off) ? s[tid - off] : 0;
        __syncthreads();
        s[tid] += t;
        __syncthreads();
    }
    if (tid < nbk) { int ex = s[tid] - v; cbase[tid] = ex; ccur[tid] = ex; }
    if (tid == 0) cbase[nbk] = E;
}

// ---- Pass 1: scatter edges into coarse-bucket runs (one global atomic per block-bucket).
// Packs (src | destlo<<20, w) so pass 2 doesn't need col[].
__global__ __launch_bounds__(TPB) void k_p1(const int* __restrict__ row,
                                            const int* __restrict__ col,
                                            const float* __restrict__ w,
                                            int* __restrict__ ccur,
                                            int2* __restrict__ bkt, int E, int nbk) {
    __shared__ int h[1024];
    __shared__ int base[1024];
    int tid = threadIdx.x;
    for (int i = tid; i < nbk; i += TPB) h[i] = 0;
    __syncthreads();
    int s0 = blockIdx.x * P1_CHUNK;
    int s1 = min(s0 + P1_CHUNK, E);
    for (int i = s0 + tid; i < s1; i += TPB) atomicAdd(&h[col[i] >> DSH], 1);
    __syncthreads();
    for (int i = tid; i < nbk; i += TPB) {
        int c = h[i];
        base[i] = c ? atomicAdd(&ccur[i], c) : 0;
        h[i] = 0;
    }
    __syncthreads();
    for (int i = s0 + tid; i < s1; i += TPB) {
        int c = col[i];
        int b = c >> DSH;
        int r = atomicAdd(&h[b], 1);
        bkt[base[b] + r] = make_int2(row[i] | ((c & (DNB - 1)) << 20), __float_as_int(w[i]));
    }
}

// ---- Pass 2: fine sort within bucket (LDS), write starts + final edges coalesced.
__global__ __launch_bounds__(TPB) void k_p2(const int2* __restrict__ bkt,
                                            const int* __restrict__ cbase,
                                            int* __restrict__ starts,
                                            int2* __restrict__ edges, int n, int E) {
    __shared__ int hist[DNB];
    __shared__ int curs[DNB];
    __shared__ int sc[DNB];
    __shared__ int2 stage[STAGE_CAP];
    int tid = threadIdx.x;
    int b = blockIdx.x;
    int s0 = cbase[b], s1 = cbase[b + 1];
    int cnt = s1 - s0;
    int nodeBase = b << DSH;
    if (tid < DNB) hist[tid] = 0;
    __syncthreads();
    for (int i = s0 + tid; i < s1; i += TPB)
        atomicAdd(&hist[(unsigned)bkt[i].x >> 20], 1);
    __syncthreads();
    int v = 0;
    if (tid < DNB) { v = hist[tid]; sc[tid] = v; }
    __syncthreads();
    for (int off = 1; off < DNB; off <<= 1) {
        int t = 0;
        if (tid < DNB && tid >= off) t = sc[tid - off];
        __syncthreads();
        if (tid < DNB) sc[tid] += t;
        __syncthreads();
    }
    if (tid < DNB) {
        int ex = sc[tid] - v;
        curs[tid] = ex;
        int node = nodeBase + tid;
        if (node < n) starts[node] = s0 + ex;
    }
    if (b == 0 && tid == 0) starts[n] = E;
    __syncthreads();
    if (cnt <= STAGE_CAP) {
        for (int i = s0 + tid; i < s1; i += TPB) {
            int2 ed = bkt[i];
            int d = (unsigned)ed.x >> 20;
            int r = atomicAdd(&curs[d], 1);
            stage[r] = make_int2(ed.x & 0xFFFFF, ed.y);
        }
        __syncthreads();
        for (int i = tid; i < cnt; i += TPB) edges[s0 + i] = stage[i];
    } else {  // overflow fallback: direct (uncoalesced but correct)
        for (int i = s0 + tid; i < s1; i += TPB) {
            int2 ed = bkt[i];
            int d = (unsigned)ed.x >> 20;
            int r = atomicAdd(&curs[d], 1);
            edges[s0 + r] = make_int2(ed.x & 0xFFFFF, ed.y);
        }
    }
}

// ---- deg/dinv from CSR (atomic-free)
__global__ __launch_bounds__(TPB) void k_degdinv(const int* __restrict__ starts,
                                                 const int2* __restrict__ edges,
                                                 float* __restrict__ dinv, int n) {
    int i = blockIdx.x * TPB + threadIdx.x;
    if (i >= n) return;
    int s0 = starts[i], s1 = starts[i + 1];
    float d = 1.0f;  // self-loop
    for (int s = s0; s < s1; ++s) d += __int_as_float(edges[s].y);
    dinv[i] = d > 0.f ? rsqrtf(d) : 0.f;
}

// ---- in-place w -> norm
__global__ __launch_bounds__(TPB) void k_normcsr(const int* __restrict__ starts,
                                                 const float* __restrict__ dinv,
                                                 int2* __restrict__ edges, int n) {
    int i = blockIdx.x * TPB + threadIdx.x;
    if (i >= n) return;
    int s0 = starts[i], s1 = starts[i + 1];
    float dn = dinv[i];
    for (int s = s0; s < s1; ++s) {
        int2 ed = edges[s];
        edges[s].y = __float_as_int(dinv[ed.x] * __int_as_float(ed.y) * dn);
    }
}

// ---- out[N,64] = in[N,64] @ W[64,64]; W + 16 input rows in LDS, 4 outputs/thread.
#define GR 16
__global__ __launch_bounds__(TPB) void k_gemm64(const float* __restrict__ in,
                                                const float* __restrict__ Wg,
                                                float* __restrict__ out, int n) {
    __shared__ float Ws[64 * 64];
    __shared__ float Is[GR * 64];
    int tid = threadIdx.x;
    #pragma unroll
    for (int i = 0; i < 16; ++i) Ws[i * TPB + tid] = Wg[i * TPB + tid];
    int rowbase = blockIdx.x * GR;
    {
        int r = rowbase + (tid >> 4);
        int c = (tid & 15) << 2;
        float4 vv = make_float4(0.f, 0.f, 0.f, 0.f);
        if (r < n) vv = *(const float4*)&in[(size_t)r * 64 + c];
        *(float4*)&Is[(tid >> 4) * 64 + c] = vv;
    }
    __syncthreads();
    int j = tid & 63, rgrp = tid >> 6;
    float acc[4] = {0.f, 0.f, 0.f, 0.f};
    #pragma unroll 16
    for (int k = 0; k < 64; ++k) {
        float wv = Ws[k * 64 + j];
        #pragma unroll
        for (int rr = 0; rr < 4; ++rr)
            acc[rr] = fmaf(Is[(rgrp * 4 + rr) * 64 + k], wv, acc[rr]);
    }
    #pragma unroll
    for (int rr = 0; rr < 4; ++rr) {
        int r = rowbase + rgrp * 4 + rr;
        if (r < n) out[(size_t)r * 64 + j] = acc[rr];
    }
}

// ---- gather-aggregate, fused self-loop + bias + optional ReLU
__global__ __launch_bounds__(TPB) void k_gather(const int* __restrict__ starts,
                                                const int2* __restrict__ edges,
                                                const float* __restrict__ hw,
                                                const float* __restrict__ dinv,
                                                const float* __restrict__ b,
                                                float* __restrict__ out,
                                                int n, int relu) {
    int idx = blockIdx.x * TPB + threadIdx.x;
    int node = idx >> 4;
    if (node >= n) return;
    int f = (idx & 15) << 2;
    int s0 = starts[node], s1 = starts[node + 1];
    float di = dinv[node];
    float sc = di * di;
    float4 hself = *(const float4*)&hw[(size_t)node * 64 + f];
    float4 bb = *(const float4*)&b[f];
    float4 acc;
    acc.x = fmaf(hself.x, sc, bb.x);
    acc.y = fmaf(hself.y, sc, bb.y);
    acc.z = fmaf(hself.z, sc, bb.z);
    acc.w = fmaf(hself.w, sc, bb.w);
    for (int e = s0; e < s1; ++e) {
        int2 ed = edges[e];
        float nm = __int_as_float(ed.y);
        float4 h = *(const float4*)&hw[(size_t)ed.x * 64 + f];
        acc.x = fmaf(h.x, nm, acc.x);
        acc.y = fmaf(h.y, nm, acc.y);
        acc.z = fmaf(h.z, nm, acc.z);
        acc.w = fmaf(h.w, nm, acc.w);
    }
    if (relu) {
        acc.x = acc.x > 0.f ? acc.x : 0.f;
        acc.y = acc.y > 0.f ? acc.y : 0.f;
        acc.z = acc.z > 0.f ? acc.z : 0.f;
        acc.w = acc.w > 0.f ? acc.w : 0.f;
    }
    *(float4*)&out[(size_t)node * 64 + f] = acc;
}

extern "C" void kernel_launch(void* const* d_in, const int* in_sizes, int n_in,
                              void* d_out, int out_size, void* d_ws, size_t ws_size,
                              hipStream_t stream) {
    const float* x = (const float*)d_in[0];
    const int* ei = (const int*)d_in[1];      // int32 on device
    const float* ew = (const float*)d_in[2];
    const float* Wl[3] = {(const float*)d_in[3], (const float*)d_in[5], (const float*)d_in[7]};
    const float* Bl[3] = {(const float*)d_in[4], (const float*)d_in[6], (const float*)d_in[8]};

    const int n = in_sizes[0] / 64;
    const int E = in_sizes[2];
    const int* row = ei;       // edge_index[0]
    const int* col = ei + E;   // edge_index[1]
    float* out = (float*)d_out;

    const int nbk = (n + DNB - 1) >> DSH;                 // coarse buckets (<=1024 for n<=131072)
    const int p1b = (E + P1_CHUNK - 1) / P1_CHUNK;

    // workspace layout (256B aligned):
    // dinv[n] | hw[n*64] (bucketbuf int2[E] aliased inside; hw written only after pass 2)
    // | starts[n+1] | chist[1024] | cbase[1025] | ccur[1024] | edges[E] int2
    char* ws = (char*)d_ws;
    size_t o = 0;
    float* dinv  = (float*)(ws + o);  o = (o + (size_t)n * 4 + 255) & ~(size_t)255;
    float* hw    = (float*)(ws + o);
    int2*  bkt   = (int2*)(ws + o);   o = (o + (size_t)n * 256 + 255) & ~(size_t)255;
    int* starts  = (int*)(ws + o);    o = (o + (size_t)(n + 1) * 4 + 255) & ~(size_t)255;
    int* chist   = (int*)(ws + o);    o = (o + 1024 * 4 + 255) & ~(size_t)255;
    int* cbase   = (int*)(ws + o);    o = (o + 1025 * 4 + 255) & ~(size_t)255;
    int* ccur    = (int*)(ws + o);    o = (o + 1024 * 4 + 255) & ~(size_t)255;
    int2* edges  = (int2*)(ws + o);

    // output 0 = x
    hipMemcpyAsync(out, x, (size_t)n * 64 * sizeof(float), hipMemcpyDeviceToDevice, stream);

    // CSR by destination: 2-level counting sort
    hipMemsetAsync(chist, 0, (size_t)nbk * 4, stream);
    k_p0<<<p1b, TPB, 0, stream>>>(col, chist, E, nbk);
    k_scanb<<<1, 1024, 0, stream>>>(chist, cbase, ccur, nbk, E);
    k_p1<<<p1b, TPB, 0, stream>>>(row, col, ew, ccur, bkt, E, nbk);
    k_p2<<<nbk, TPB, 0, stream>>>(bkt, cbase, starts, edges, n, E);

    // degrees + norms from CSR, atomic-free
    k_degdinv<<<(n + TPB - 1) / TPB, TPB, 0, stream>>>(starts, edges, dinv, n);
    k_normcsr<<<(n + TPB - 1) / TPB, TPB, 0, stream>>>(starts, dinv, edges, n);

    const float* hin = x;
    for (int L = 0; L < 3; ++L) {
        float* oseg = out + (size_t)(L + 1) * n * 64;
        k_gemm64<<<(n + GR - 1) / GR, TPB, 0, stream>>>(hin, Wl[L], hw, n);
        k_gather<<<(n * 16 + TPB - 1) / TPB, TPB, 0, stream>>>(starts, edges, hw, dinv, Bl[L], oseg, n, L < 2 ? 1 : 0);
        hin = oseg;
    }
}

// Round 6
// 455.296 us; speedup vs baseline: 7.9894x; 1.0747x over previous
//
#include <hip/hip_runtime.h>

// GCN: 3x (h@W -> gather-aggregate via CSR-by-dest + self-loop + bias [-> ReLU])
// Outputs: concat(x, h1, h2, h3), each [N,64] fp32.
// CSR via 2-level counting sort; deg/dinv fused into pass 2; gather unrolled x4 for MLP.

#define TPB 256
#define P1_CHUNK 8192   // edges per block in pass0/pass1
#define DSH 7           // coarse bucket = dest >> DSH (128 dests/bucket)
#define DNB 128         // dests per bucket
#define STAGE_CAP 4096  // pass-2 LDS staging capacity (edges)

// ---- Pass 0: coarse histogram (per-block LDS hist, merged with few global atomics)
__global__ __launch_bounds__(TPB) void k_p0(const int* __restrict__ col,
                                            int* __restrict__ chist, int E, int nbk) {
    __shared__ int h[1024];
    int tid = threadIdx.x;
    for (int i = tid; i < nbk; i += TPB) h[i] = 0;
    __syncthreads();
    int s0 = blockIdx.x * P1_CHUNK;
    int s1 = min(s0 + P1_CHUNK, E);
    for (int i = s0 + tid; i < s1; i += TPB) atomicAdd(&h[col[i] >> DSH], 1);
    __syncthreads();
    for (int i = tid; i < nbk; i += TPB)
        if (h[i]) atomicAdd(&chist[i], h[i]);
}

// ---- Scan coarse buckets (single block), init cursor copy.
__global__ __launch_bounds__(1024) void k_scanb(const int* __restrict__ chist,
                                                int* __restrict__ cbase,
                                                int* __restrict__ ccur, int nbk, int E) {
    __shared__ int s[1024];
    int tid = threadIdx.x;
    int v = (tid < nbk) ? chist[tid] : 0;
    s[tid] = v;
    __syncthreads();
    for (int off = 1; off < 1024; off <<= 1) {
        int t = (tid >= off) ? s[tid - off] : 0;
        __syncthreads();
        s[tid] += t;
        __syncthreads();
    }
    if (tid < nbk) { int ex = s[tid] - v; cbase[tid] = ex; ccur[tid] = ex; }
    if (tid == 0) cbase[nbk] = E;
}

// ---- Pass 1: scatter edges into coarse-bucket runs (one global atomic per block-bucket).
// Packs (src | destlo<<20, w) so pass 2 doesn't need col[].
__global__ __launch_bounds__(TPB) void k_p1(const int* __restrict__ row,
                                            const int* __restrict__ col,
                                            const float* __restrict__ w,
                                            int* __restrict__ ccur,
                                            int2* __restrict__ bkt, int E, int nbk) {
    __shared__ int h[1024];
    __shared__ int base[1024];
    int tid = threadIdx.x;
    for (int i = tid; i < nbk; i += TPB) h[i] = 0;
    __syncthreads();
    int s0 = blockIdx.x * P1_CHUNK;
    int s1 = min(s0 + P1_CHUNK, E);
    for (int i = s0 + tid; i < s1; i += TPB) atomicAdd(&h[col[i] >> DSH], 1);
    __syncthreads();
    for (int i = tid; i < nbk; i += TPB) {
        int c = h[i];
        base[i] = c ? atomicAdd(&ccur[i], c) : 0;
        h[i] = 0;
    }
    __syncthreads();
    for (int i = s0 + tid; i < s1; i += TPB) {
        int c = col[i];
        int b = c >> DSH;
        int r = atomicAdd(&h[b], 1);
        bkt[base[b] + r] = make_int2(row[i] | ((c & (DNB - 1)) << 20), __float_as_int(w[i]));
    }
}

// ---- Pass 2: fine sort within bucket (LDS), write starts + edges coalesced,
//      and compute deg/dinv per dest (its edges are all here).
__global__ __launch_bounds__(TPB) void k_p2(const int2* __restrict__ bkt,
                                            const int* __restrict__ cbase,
                                            int* __restrict__ starts,
                                            int2* __restrict__ edges,
                                            float* __restrict__ dinv, int n, int E) {
    __shared__ int hist[DNB];
    __shared__ int curs[DNB];
    __shared__ int sc[DNB];
    __shared__ int2 stage[STAGE_CAP];
    int tid = threadIdx.x;
    int b = blockIdx.x;
    int s0 = cbase[b], s1 = cbase[b + 1];
    int cnt = s1 - s0;
    int nodeBase = b << DSH;
    if (tid < DNB) hist[tid] = 0;
    __syncthreads();
    for (int i = s0 + tid; i < s1; i += TPB)
        atomicAdd(&hist[(unsigned)bkt[i].x >> 20], 1);
    __syncthreads();
    int v = 0;
    if (tid < DNB) { v = hist[tid]; sc[tid] = v; }
    __syncthreads();
    for (int off = 1; off < DNB; off <<= 1) {
        int t = 0;
        if (tid < DNB && tid >= off) t = sc[tid - off];
        __syncthreads();
        if (tid < DNB) sc[tid] += t;
        __syncthreads();
    }
    if (tid < DNB) {
        int ex = sc[tid] - v;
        curs[tid] = ex;
        int node = nodeBase + tid;
        if (node < n) starts[node] = s0 + ex;
    }
    if (b == 0 && tid == 0) starts[n] = E;
    __syncthreads();
    if (cnt <= STAGE_CAP) {
        for (int i = s0 + tid; i < s1; i += TPB) {
            int2 ed = bkt[i];
            int d = (unsigned)ed.x >> 20;
            int r = atomicAdd(&curs[d], 1);
            stage[r] = make_int2(ed.x & 0xFFFFF, ed.y);
        }
        __syncthreads();
        for (int i = tid; i < cnt; i += TPB) edges[s0 + i] = stage[i];
        // deg/dinv from LDS stage: node tid's run = [sc[tid]-v, sc[tid])
        if (tid < DNB) {
            int node = nodeBase + tid;
            if (node < n) {
                float d = 1.0f;  // self-loop
                for (int j = sc[tid] - v; j < sc[tid]; ++j)
                    d += __int_as_float(stage[j].y);
                dinv[node] = rsqrtf(d);
            }
        }
    } else {  // overflow fallback: direct (uncoalesced but correct)
        for (int i = s0 + tid; i < s1; i += TPB) {
            int2 ed = bkt[i];
            int d = (unsigned)ed.x >> 20;
            int r = atomicAdd(&curs[d], 1);
            edges[s0 + r] = make_int2(ed.x & 0xFFFFF, ed.y);
        }
        __syncthreads();
        if (tid < DNB) {
            int node = nodeBase + tid;
            if (node < n) {
                float d = 1.0f;
                for (int j = sc[tid] - v; j < sc[tid]; ++j)
                    d += __int_as_float(edges[s0 + j].y);
                dinv[node] = rsqrtf(d);
            }
        }
    }
}

// ---- in-place w -> norm (dinv[src]*w*dinv[dest])
__global__ __launch_bounds__(TPB) void k_normcsr(const int* __restrict__ starts,
                                                 const float* __restrict__ dinv,
                                                 int2* __restrict__ edges, int n) {
    int i = blockIdx.x * TPB + threadIdx.x;
    if (i >= n) return;
    int s0 = starts[i], s1 = starts[i + 1];
    float dn = dinv[i];
    for (int s = s0; s < s1; ++s) {
        int2 ed = edges[s];
        edges[s].y = __float_as_int(dinv[ed.x] * __int_as_float(ed.y) * dn);
    }
}

// ---- out[N,64] = in[N,64] @ W[64,64]; W + 16 input rows in LDS, 4 outputs/thread.
#define GR 16
__global__ __launch_bounds__(TPB) void k_gemm64(const float* __restrict__ in,
                                                const float* __restrict__ Wg,
                                                float* __restrict__ out, int n) {
    __shared__ float Ws[64 * 64];
    __shared__ float Is[GR * 64];
    int tid = threadIdx.x;
    #pragma unroll
    for (int i = 0; i < 16; ++i) Ws[i * TPB + tid] = Wg[i * TPB + tid];
    int rowbase = blockIdx.x * GR;
    {
        int r = rowbase + (tid >> 4);
        int c = (tid & 15) << 2;
        float4 vv = make_float4(0.f, 0.f, 0.f, 0.f);
        if (r < n) vv = *(const float4*)&in[(size_t)r * 64 + c];
        *(float4*)&Is[(tid >> 4) * 64 + c] = vv;
    }
    __syncthreads();
    int j = tid & 63, rgrp = tid >> 6;
    float acc[4] = {0.f, 0.f, 0.f, 0.f};
    #pragma unroll 16
    for (int k = 0; k < 64; ++k) {
        float wv = Ws[k * 64 + j];
        #pragma unroll
        for (int rr = 0; rr < 4; ++rr)
            acc[rr] = fmaf(Is[(rgrp * 4 + rr) * 64 + k], wv, acc[rr]);
    }
    #pragma unroll
    for (int rr = 0; rr < 4; ++rr) {
        int r = rowbase + rgrp * 4 + rr;
        if (r < n) out[(size_t)r * 64 + j] = acc[rr];
    }
}

// ---- gather-aggregate, unrolled x4 for memory-level parallelism.
__global__ __launch_bounds__(TPB) void k_gather(const int* __restrict__ starts,
                                                const int2* __restrict__ edges,
                                                const float* __restrict__ hw,
                                                const float* __restrict__ dinv,
                                                const float* __restrict__ b,
                                                float* __restrict__ out,
                                                int n, int relu) {
    int idx = blockIdx.x * TPB + threadIdx.x;
    int node = idx >> 4;
    if (node >= n) return;
    int f = (idx & 15) << 2;
    int s0 = starts[node], s1 = starts[node + 1];
    float di = dinv[node];
    float sc = di * di;
    float4 hself = *(const float4*)&hw[(size_t)node * 64 + f];
    float4 bb = *(const float4*)&b[f];
    float4 acc;
    acc.x = fmaf(hself.x, sc, bb.x);
    acc.y = fmaf(hself.y, sc, bb.y);
    acc.z = fmaf(hself.z, sc, bb.z);
    acc.w = fmaf(hself.w, sc, bb.w);
    int e = s0;
    for (; e + 4 <= s1; e += 4) {
        int2 e0 = edges[e + 0];
        int2 e1 = edges[e + 1];
        int2 e2 = edges[e + 2];
        int2 e3 = edges[e + 3];
        float4 h0 = *(const float4*)&hw[(size_t)e0.x * 64 + f];
        float4 h1 = *(const float4*)&hw[(size_t)e1.x * 64 + f];
        float4 h2 = *(const float4*)&hw[(size_t)e2.x * 64 + f];
        float4 h3 = *(const float4*)&hw[(size_t)e3.x * 64 + f];
        float n0 = __int_as_float(e0.y), n1 = __int_as_float(e1.y);
        float n2 = __int_as_float(e2.y), n3 = __int_as_float(e3.y);
        acc.x = fmaf(h0.x, n0, acc.x); acc.y = fmaf(h0.y, n0, acc.y);
        acc.z = fmaf(h0.z, n0, acc.z); acc.w = fmaf(h0.w, n0, acc.w);
        acc.x = fmaf(h1.x, n1, acc.x); acc.y = fmaf(h1.y, n1, acc.y);
        acc.z = fmaf(h1.z, n1, acc.z); acc.w = fmaf(h1.w, n1, acc.w);
        acc.x = fmaf(h2.x, n2, acc.x); acc.y = fmaf(h2.y, n2, acc.y);
        acc.z = fmaf(h2.z, n2, acc.z); acc.w = fmaf(h2.w, n2, acc.w);
        acc.x = fmaf(h3.x, n3, acc.x); acc.y = fmaf(h3.y, n3, acc.y);
        acc.z = fmaf(h3.z, n3, acc.z); acc.w = fmaf(h3.w, n3, acc.w);
    }
    for (; e < s1; ++e) {
        int2 ed = edges[e];
        float nm = __int_as_float(ed.y);
        float4 h = *(const float4*)&hw[(size_t)ed.x * 64 + f];
        acc.x = fmaf(h.x, nm, acc.x);
        acc.y = fmaf(h.y, nm, acc.y);
        acc.z = fmaf(h.z, nm, acc.z);
        acc.w = fmaf(h.w, nm, acc.w);
    }
    if (relu) {
        acc.x = acc.x > 0.f ? acc.x : 0.f;
        acc.y = acc.y > 0.f ? acc.y : 0.f;
        acc.z = acc.z > 0.f ? acc.z : 0.f;
        acc.w = acc.w > 0.f ? acc.w : 0.f;
    }
    *(float4*)&out[(size_t)node * 64 + f] = acc;
}

extern "C" void kernel_launch(void* const* d_in, const int* in_sizes, int n_in,
                              void* d_out, int out_size, void* d_ws, size_t ws_size,
                              hipStream_t stream) {
    const float* x = (const float*)d_in[0];
    const int* ei = (const int*)d_in[1];      // int32 on device
    const float* ew = (const float*)d_in[2];
    const float* Wl[3] = {(const float*)d_in[3], (const float*)d_in[5], (const float*)d_in[7]};
    const float* Bl[3] = {(const float*)d_in[4], (const float*)d_in[6], (const float*)d_in[8]};

    const int n = in_sizes[0] / 64;
    const int E = in_sizes[2];
    const int* row = ei;       // edge_index[0]
    const int* col = ei + E;   // edge_index[1]
    float* out = (float*)d_out;

    const int nbk = (n + DNB - 1) >> DSH;                 // coarse buckets (<=1024 for n<=131072)
    const int p1b = (E + P1_CHUNK - 1) / P1_CHUNK;

    // workspace layout (256B aligned):
    // dinv[n] | hw[n*64] (bkt int2[E] aliased inside; hw written only after pass 2)
    // | starts[n+1] | chist[1024] | cbase[1025] | ccur[1024] | edges[E] int2
    char* ws = (char*)d_ws;
    size_t o = 0;
    float* dinv  = (float*)(ws + o);  o = (o + (size_t)n * 4 + 255) & ~(size_t)255;
    float* hw    = (float*)(ws + o);
    int2*  bkt   = (int2*)(ws + o);   o = (o + (size_t)n * 256 + 255) & ~(size_t)255;
    int* starts  = (int*)(ws + o);    o = (o + (size_t)(n + 1) * 4 + 255) & ~(size_t)255;
    int* chist   = (int*)(ws + o);    o = (o + 1024 * 4 + 255) & ~(size_t)255;
    int* cbase   = (int*)(ws + o);    o = (o + 1025 * 4 + 255) & ~(size_t)255;
    int* ccur    = (int*)(ws + o);    o = (o + 1024 * 4 + 255) & ~(size_t)255;
    int2* edges  = (int2*)(ws + o);

    // output 0 = x
    hipMemcpyAsync(out, x, (size_t)n * 64 * sizeof(float), hipMemcpyDeviceToDevice, stream);

    // CSR by destination: 2-level counting sort (+ fused deg/dinv in pass 2)
    hipMemsetAsync(chist, 0, (size_t)nbk * 4, stream);
    k_p0<<<p1b, TPB, 0, stream>>>(col, chist, E, nbk);
    k_scanb<<<1, 1024, 0, stream>>>(chist, cbase, ccur, nbk, E);
    k_p1<<<p1b, TPB, 0, stream>>>(row, col, ew, ccur, bkt, E, nbk);
    k_p2<<<nbk, TPB, 0, stream>>>(bkt, cbase, starts, edges, dinv, n, E);
    k_normcsr<<<(n + TPB - 1) / TPB, TPB, 0, stream>>>(starts, dinv, edges, n);

    const float* hin = x;
    for (int L = 0; L < 3; ++L) {
        float* oseg = out + (size_t)(L + 1) * n * 64;
        k_gemm64<<<(n + GR - 1) / GR, TPB, 0, stream>>>(hin, Wl[L], hw, n);
        k_gather<<<(n * 16 + TPB - 1) / TPB, TPB, 0, stream>>>(starts, edges, hw, dinv, Bl[L], oseg, n, L < 2 ? 1 : 0);
        hin = oseg;
    }
}